// Round 10
// baseline (77.860 us; speedup 1.0000x reference)
//
#include <hip/hip_runtime.h>
#include <math.h>

#define OUT_H 7
#define OUT_W 7
#define NBINS 49

// R9's validated wave-per-(n,c) logic (absmax 0), repacked as 4 waves/block:
// 8192 x 256-thread blocks instead of 32768 x 64-thread blocks. CDNA caps
// workgroups/CU at 16, so single-wave blocks topped out at 16 waves/CU (50%);
// 256-thread blocks reach 8 wg x 4 waves = 32 waves/CU (100%) and cut
// workgroup dispatches 4x. All memory accesses statically unrolled with
// index clamping (duplicates harmless under max): phase 1 = 28 (+28 iff
// roi_h>28, wave-uniform) global loads -> ONE vmcnt exposure; phase 2 =
// 8 ds_reads -> ONE lgkmcnt exposure. Wave-private LDS slices -> no barriers.
// Bin bounds: exact integer floor(k*roi/7) == (k*roi)/7.
// Grid bx = n*64+cg, c = cg*4+wave: XCD = cg%8 -> each XCD re-reads a fixed
// 2MB channel subset that fits its 4MB L2.
__global__ __launch_bounds__(256) void roipool_v10(
    const float* __restrict__ feat, const int* __restrict__ rois,
    float* __restrict__ out)
{
    constexpr int C = 256, H = 64, W = 64;
    __shared__ float racc_lds[4][OUT_H][W + 1];   // per-wave slice, +1 pad

    const int bx   = blockIdx.x;
    const int n    = bx >> 6;          // roi (128)
    const int cg   = bx & 63;          // channel group
    const int tid  = threadIdx.x;
    const int lane = tid & 63;         // == x
    const int wave = tid >> 6;
    const int c    = cg * 4 + wave;

    const int* r = rois + n * 5;
    const int b  = r[0];
    const int x1 = r[1];
    const int y1 = r[2];
    const int roi_w = r[3] - x1 + 1;
    const int roi_h = r[4] - y1 + 1;

    const float* plane = feat + ((size_t)(b * C + c)) * (H * W);

    int hb[OUT_H + 1];                 // statically indexed -> registers
#pragma unroll
    for (int k = 0; k <= OUT_H; ++k) hb[k] = (k * roi_h) / OUT_H;

    float racc[OUT_H];
    {
        float v[OUT_H][4];
#pragma unroll
        for (int ph = 0; ph < OUT_H; ++ph) {
            const int yb = y1 + hb[ph];
            int yl = y1 + hb[ph + 1] - 1;   // last row of bin
            yl = yl > yb ? yl : yb;         // empty-bin guard (stays in-image)
#pragma unroll
            for (int j = 0; j < 4; ++j) {
                int y = yb + j;
                y = y < yl ? y : yl;        // clamp: duplicate rows, same bin
                v[ph][j] = plane[y * W + lane];   // coalesced 256B
            }
        }
#pragma unroll
        for (int ph = 0; ph < OUT_H; ++ph)
            racc[ph] = fmaxf(fmaxf(v[ph][0], v[ph][1]),
                             fmaxf(v[ph][2], v[ph][3]));
    }
    if (roi_h > 28) {   // uniform: only then can a bin exceed 4 rows (max 7)
        float v[OUT_H][4];
#pragma unroll
        for (int ph = 0; ph < OUT_H; ++ph) {
            const int yb = y1 + hb[ph];
            const int yl = y1 + hb[ph + 1] - 1;  // cnt>=4 here, yl>=yb+3
#pragma unroll
            for (int j = 0; j < 4; ++j) {
                int y = yb + 4 + j;
                y = y < yl ? y : yl;
                v[ph][j] = plane[y * W + lane];
            }
        }
#pragma unroll
        for (int ph = 0; ph < OUT_H; ++ph)
            racc[ph] = fmaxf(racc[ph],
                             fmaxf(fmaxf(v[ph][0], v[ph][1]),
                                   fmaxf(v[ph][2], v[ph][3])));
    }

    // Wave-private LDS round-trip (same-wave ordering: no barrier needed).
#pragma unroll
    for (int ph = 0; ph < OUT_H; ++ph) racc_lds[wave][ph][lane] = racc[ph];

    if (lane < NBINS) {
        const int ph = lane / OUT_W;
        const int pw = lane - ph * OUT_W;

        const int hsL = (ph * roi_h) / OUT_H;        // per-lane validity
        const int heL = ((ph + 1) * roi_h) / OUT_H;
        const int ws  = (pw * roi_w) / OUT_W;
        const int we  = ((pw + 1) * roi_w) / OUT_W;

        const int xs = x1 + ws;
        int xl = x1 + we - 1;
        xl = xl > xs ? xl : xs;          // empty-bin guard

        float g[8];                      // max bin width = ceil(48/7) = 7 <= 8
#pragma unroll
        for (int j = 0; j < 8; ++j) {
            int x = xs + j;
            x = x < xl ? x : xl;         // clamp: duplicates harmless
            g[j] = racc_lds[wave][ph][x];
        }
        float m = fmaxf(fmaxf(fmaxf(g[0], g[1]), fmaxf(g[2], g[3])),
                        fmaxf(fmaxf(g[4], g[5]), fmaxf(g[6], g[7])));

        const bool valid = (heL > hsL) && (we > ws);
        // out[n][c][ph][pw]: 49 contiguous floats per wave
        out[((size_t)(n * C + c)) * NBINS + lane] = valid ? m : 0.0f;
    }
}

extern "C" void kernel_launch(void* const* d_in, const int* in_sizes, int n_in,
                              void* d_out, int out_size, void* d_ws, size_t ws_size,
                              hipStream_t stream) {
    const float* feat = (const float*)d_in[0];
    const int*   rois = (const int*)d_in[1];
    float*       out  = (float*)d_out;

    const int N = in_sizes[1] / 5;     // 128 rois
    const int n_blocks = N * 64;       // 4 waves/block, one wave per (n,c)

    roipool_v10<<<n_blocks, 256, 0, stream>>>(feat, rois, out);
}